// Round 13
// baseline (322.932 us; speedup 1.0000x reference)
//
#include <hip/hip_runtime.h>
#include <hip/hip_fp16.h>

#define DI __device__ __forceinline__

typedef __attribute__((ext_vector_type(4))) float f32x4;
typedef __attribute__((ext_vector_type(8))) _Float16 f16x8;
typedef __attribute__((ext_vector_type(8))) short s16x8;

DI unsigned short f2h(float f) { return __half_as_ushort(__float2half(f)); }
DI float h2f(unsigned short u) { return __half2float(__ushort_as_half(u)); }

#define MFMA16(A, B, C) (C) = __builtin_amdgcn_mfma_f32_16x16x32_f16((A), (B), (C), 0, 0, 0)

// ---------------------------------------------------------------------------
// Prep: weight-norm fold + diag-scale fold, emitting MFMA-FRAGMENT layout:
//   W'[kj][s][n16][lane(l4*16+l15)][8]; a wave's B-frag load = contiguous 1KB.
// ---------------------------------------------------------------------------
struct PrepArgs {
    const float *adj;
    const float *v0,*g0,*b0,*v1,*g1,*b1,*v2,*g2,*b2,*v3,*g3,*b3,*v4,*g4,*b4;
    unsigned short *w0,*w1,*w2,*w3;
    float *w4, *bias0,*bias1,*bias2,*bias3,*bias4;
};

template <int CIN, int CINPAD>
DI void prep_row(const float* __restrict__ v, const float* __restrict__ g,
                 const float* __restrict__ b, const float* __restrict__ adj,
                 int cout, int use_scale,
                 unsigned short* __restrict__ wout, float* __restrict__ biasout,
                 int ridx, int lane)
{
    const int k = ridx / cout;
    const int o = ridx - k * cout;
    const float* vr = v + (size_t)ridx * CIN;
    float xv[8];
    if (lane * 8 < CIN) {
        const f32x4 p0 = *reinterpret_cast<const f32x4*>(&vr[lane * 8]);
        const f32x4 p1 = *reinterpret_cast<const f32x4*>(&vr[lane * 8 + 4]);
        #pragma unroll
        for (int e = 0; e < 4; e++) { xv[e] = p0[e]; xv[4 + e] = p1[e]; }
    } else {
        #pragma unroll
        for (int e = 0; e < 8; e++) xv[e] = 0.f;
    }
    float ss = 0.f;
    #pragma unroll
    for (int e = 0; e < 8; e++) ss += xv[e] * xv[e];
    #pragma unroll
    for (int off = 32; off >= 1; off >>= 1) ss += __shfl_xor(ss, off, 64);
    float s = g[ridx] / sqrtf(ss);
    float bias = b[ridx];
    if (use_scale) {
        float d = adj[k * 81];            // adj[k][k]
        d = d > 0.f ? d : 0.f;
        s *= d; bias *= d;                // leaky(z)*s == leaky(z*s), s>=0
    }
    if (lane == 0) biasout[ridx] = bias;
    if (lane < CINPAD / 8) {
        unsigned short tmp[8];
        #pragma unroll
        for (int e = 0; e < 8; e++) tmp[e] = f2h(xv[e] * s);
        unsigned short* wj = wout + (size_t)k * cout * CINPAD;
        const int sblk = lane >> 2, l4w = lane & 3;
        const size_t pos = (((size_t)sblk * (cout >> 4) + (o >> 4)) * 64 + l4w * 16 + (o & 15)) * 8;
        *reinterpret_cast<s16x8*>(&wj[pos]) = *reinterpret_cast<const s16x8*>(tmp);
    }
}

DI void prep_w4_row(const float* __restrict__ v, const float* __restrict__ g,
                    const float* __restrict__ b, float* __restrict__ wout,
                    float* __restrict__ biasout, int ridx, int lane)
{
    const float x = v[(size_t)ridx * 64 + lane];
    float ss = x * x;
    #pragma unroll
    for (int off = 32; off >= 1; off >>= 1) ss += __shfl_xor(ss, off, 64);
    const float s = g[ridx] / sqrtf(ss);
    if (lane == 0) biasout[ridx] = b[ridx];
    wout[(size_t)ridx * 64 + lane] = x * s;
}

__global__ __launch_bounds__(256) void prep_kernel(PrepArgs a)
{
    const int bid = blockIdx.x, wave = threadIdx.x >> 6, lane = threadIdx.x & 63;
    if (bid < 10240)      prep_row<480, 512>(a.v0, a.g0, a.b0, a.adj, 512, 1, a.w0, a.bias0, bid * 4 + wave, lane);
    else if (bid < 15360) prep_row<512, 512>(a.v1, a.g1, a.b1, a.adj, 256, 1, a.w1, a.bias1, (bid - 10240) * 4 + wave, lane);
    else if (bid < 17920) prep_row<256, 256>(a.v2, a.g2, a.b2, a.adj, 128, 1, a.w2, a.bias2, (bid - 15360) * 4 + wave, lane);
    else if (bid < 19200) prep_row<128, 128>(a.v3, a.g3, a.b3, a.adj,  64, 0, a.w3, a.bias3, (bid - 17920) * 4 + wave, lane);
    else                  prep_w4_row(a.v4, a.g4, a.b4, a.w4, a.bias4, (bid - 19200) * 4 + wave, lane);
}

// ---------------------------------------------------------------------------
// Mega v6 = v5 with the XOR swizzle replaced by +16B row padding (LDP=520
// shorts; 1040B stride = 4-bank rotation/row, conflict-equivalent), so all
// LDS accesses are base-reg + immediate; prologue computes each RFF dot once
// (cos AND sin); stage 4 parallelized over 384 threads.
// ---------------------------------------------------------------------------
struct MegaArgs {
    const float *qp, *pf, *Brff;
    const unsigned short *w0, *w1, *w2, *w3;
    const float *w4, *bias0, *bias1, *bias2, *bias3, *bias4;
    float* out;
};

constexpr int LDP = 520;   // padded row stride in shorts

__global__ __launch_bounds__(512, 4) void mega6_kernel(MegaArgs a)
{
    extern __shared__ __align__(16) unsigned short R0[];   // [64][520] = 66560 B
    const int tid = threadIdx.x, wid = tid >> 6, lane = tid & 63;
    const int l15 = lane & 15, l4 = lane >> 4;
    const int bid = blockIdx.x;
    const int swz = (bid & 7) * 320 + (bid >> 3);   // XCD-chunked, bijective (2560%8==0)
    const int kj = swz >> 5;
    const int m0 = (swz & 31) * 64;

    // ---- prologue: h0 = pf + RFF(qp) -> R0 [64][LDP], cols 0..479 real, 480..511 zero
    {
        const int row = tid >> 3, tq = tid & 7;
        const int gr = (m0 + row) * 80 + kj;      // batch-major global row
        const float q0 = a.qp[gr * 3 + 0], q1 = a.qp[gr * 3 + 1], q2 = a.qp[gr * 3 + 2];
        #pragma unroll
        for (int i = 0; i < 4; i++) {
            const int jc = tq + i * 8;            // 0..31
            if (jc < 30) {
                const int c0 = jc * 8;            // 0..232
                const f32x4 b0a = *reinterpret_cast<const f32x4*>(&a.Brff[c0]);
                const f32x4 b0b = *reinterpret_cast<const f32x4*>(&a.Brff[c0 + 4]);
                const f32x4 b1a = *reinterpret_cast<const f32x4*>(&a.Brff[240 + c0]);
                const f32x4 b1b = *reinterpret_cast<const f32x4*>(&a.Brff[240 + c0 + 4]);
                const f32x4 b2a = *reinterpret_cast<const f32x4*>(&a.Brff[480 + c0]);
                const f32x4 b2b = *reinterpret_cast<const f32x4*>(&a.Brff[480 + c0 + 4]);
                const f32x4 pc0 = __builtin_nontemporal_load(
                    reinterpret_cast<const f32x4*>(&a.pf[(size_t)gr * 480 + c0]));
                const f32x4 pc1 = __builtin_nontemporal_load(
                    reinterpret_cast<const f32x4*>(&a.pf[(size_t)gr * 480 + c0 + 4]));
                const f32x4 ps0 = __builtin_nontemporal_load(
                    reinterpret_cast<const f32x4*>(&a.pf[(size_t)gr * 480 + c0 + 240]));
                const f32x4 ps1 = __builtin_nontemporal_load(
                    reinterpret_cast<const f32x4*>(&a.pf[(size_t)gr * 480 + c0 + 244]));
                unsigned short oc[8], os[8];
                #pragma unroll
                for (int e = 0; e < 4; e++) {
                    float rev = q0 * b0a[e] + q1 * b1a[e] + q2 * b2a[e];
                    rev -= floorf(rev);           // v_sin/v_cos take revolutions
                    oc[e] = f2h(pc0[e] + __builtin_amdgcn_cosf(rev));
                    os[e] = f2h(ps0[e] + __builtin_amdgcn_sinf(rev));
                }
                #pragma unroll
                for (int e = 0; e < 4; e++) {
                    float rev = q0 * b0b[e] + q1 * b1b[e] + q2 * b2b[e];
                    rev -= floorf(rev);
                    oc[4 + e] = f2h(pc1[e] + __builtin_amdgcn_cosf(rev));
                    os[4 + e] = f2h(ps1[e] + __builtin_amdgcn_sinf(rev));
                }
                *reinterpret_cast<s16x8*>(&R0[row * LDP + c0]) = *reinterpret_cast<const s16x8*>(oc);
                *reinterpret_cast<s16x8*>(&R0[row * LDP + c0 + 240]) = *reinterpret_cast<const s16x8*>(os);
            } else {
                const s16x8 z = {0, 0, 0, 0, 0, 0, 0, 0};
                const int c0 = 480 + (jc - 30) * 16;   // 480 or 496
                *reinterpret_cast<s16x8*>(&R0[row * LDP + c0]) = z;
                *reinterpret_cast<s16x8*>(&R0[row * LDP + c0 + 8]) = z;
            }
        }
    }
    __syncthreads();

    const int abase = l15 * LDP + l4 * 8;         // shared A-frag base (rows f*16+l15)

    // ---- stage 0: h1 = leaky(h0 @ w0^T + b0).  N=512 (wave owns 64 cols), K=512.
    {
        const unsigned short* Wb = a.w0 + (size_t)kj * 262144 + (size_t)(wid * 4) * 512 + lane * 8;
        f32x4 acc[4][4] = {};
        f16x8 bfA[4], bfB[4];
        #pragma unroll
        for (int g = 0; g < 4; g++) bfA[g] = *reinterpret_cast<const f16x8*>(Wb + g * 512);
        #pragma unroll
        for (int ss = 0; ss < 8; ss++) {
            const int s0 = ss * 2, s1 = ss * 2 + 1;
            f16x8 af0[4];
            #pragma unroll
            for (int f = 0; f < 4; f++)
                af0[f] = *reinterpret_cast<const f16x8*>(&R0[abase + f * 16 * LDP + s0 * 32]);
            #pragma unroll
            for (int g = 0; g < 4; g++)
                bfB[g] = *reinterpret_cast<const f16x8*>(Wb + (size_t)s1 * 16384 + g * 512);
            #pragma unroll
            for (int f = 0; f < 4; f++)
                #pragma unroll
                for (int g = 0; g < 4; g++)
                    MFMA16(af0[f], bfA[g], acc[f][g]);
            f16x8 af1[4];
            #pragma unroll
            for (int f = 0; f < 4; f++)
                af1[f] = *reinterpret_cast<const f16x8*>(&R0[abase + f * 16 * LDP + s1 * 32]);
            if (ss < 7) {
                #pragma unroll
                for (int g = 0; g < 4; g++)
                    bfA[g] = *reinterpret_cast<const f16x8*>(Wb + (size_t)(s0 + 2) * 16384 + g * 512);
            }
            #pragma unroll
            for (int f = 0; f < 4; f++)
                #pragma unroll
                for (int g = 0; g < 4; g++)
                    MFMA16(af1[f], bfB[g], acc[f][g]);
        }
        __syncthreads();                          // all h0 reads done
        float bv[4];
        #pragma unroll
        for (int g = 0; g < 4; g++) bv[g] = a.bias0[kj * 512 + wid * 64 + g * 16 + l15];
        const int wb = (l4 * 4) * LDP + wid * 64 + l15;
        #pragma unroll
        for (int f = 0; f < 4; f++)
            #pragma unroll
            for (int g = 0; g < 4; g++)
                #pragma unroll
                for (int r = 0; r < 4; r++) {
                    float z = acc[f][g][r] + bv[g];
                    z = z >= 0.f ? z : 0.01f * z;
                    R0[wb + (f * 16 + r) * LDP + g * 16] = f2h(z);
                }
    }
    __syncthreads();

    // ---- stage 1: h2 = leaky(h1 @ w1^T + b1).  N=256 (wave owns 32), K=512.
    {
        const unsigned short* Wb = a.w1 + (size_t)kj * 131072 + (size_t)(wid * 2) * 512 + lane * 8;
        f32x4 acc[4][2] = {};
        f16x8 bfA[2], bfB[2];
        #pragma unroll
        for (int g = 0; g < 2; g++) bfA[g] = *reinterpret_cast<const f16x8*>(Wb + g * 512);
        #pragma unroll
        for (int ss = 0; ss < 8; ss++) {
            const int s0 = ss * 2, s1 = ss * 2 + 1;
            f16x8 af0[4];
            #pragma unroll
            for (int f = 0; f < 4; f++)
                af0[f] = *reinterpret_cast<const f16x8*>(&R0[abase + f * 16 * LDP + s0 * 32]);
            #pragma unroll
            for (int g = 0; g < 2; g++)
                bfB[g] = *reinterpret_cast<const f16x8*>(Wb + (size_t)s1 * 8192 + g * 512);
            #pragma unroll
            for (int f = 0; f < 4; f++)
                #pragma unroll
                for (int g = 0; g < 2; g++)
                    MFMA16(af0[f], bfA[g], acc[f][g]);
            f16x8 af1[4];
            #pragma unroll
            for (int f = 0; f < 4; f++)
                af1[f] = *reinterpret_cast<const f16x8*>(&R0[abase + f * 16 * LDP + s1 * 32]);
            if (ss < 7) {
                #pragma unroll
                for (int g = 0; g < 2; g++)
                    bfA[g] = *reinterpret_cast<const f16x8*>(Wb + (size_t)(s0 + 2) * 8192 + g * 512);
            }
            #pragma unroll
            for (int f = 0; f < 4; f++)
                #pragma unroll
                for (int g = 0; g < 2; g++)
                    MFMA16(af1[f], bfB[g], acc[f][g]);
        }
        __syncthreads();
        float bv[2];
        #pragma unroll
        for (int g = 0; g < 2; g++) bv[g] = a.bias1[kj * 256 + wid * 32 + g * 16 + l15];
        const int wb = (l4 * 4) * LDP + wid * 32 + l15;
        #pragma unroll
        for (int f = 0; f < 4; f++)
            #pragma unroll
            for (int g = 0; g < 2; g++)
                #pragma unroll
                for (int r = 0; r < 4; r++) {
                    float z = acc[f][g][r] + bv[g];
                    z = z >= 0.f ? z : 0.01f * z;
                    R0[wb + (f * 16 + r) * LDP + g * 16] = f2h(z);
                }
    }
    __syncthreads();

    // ---- stage 2: h3 = leaky(h2 @ w2^T + b2).  N=128 (wave owns 16), K=256.
    {
        const unsigned short* Wb = a.w2 + (size_t)kj * 32768 + (size_t)wid * 512 + lane * 8;
        f32x4 acc[4] = {};
        f16x8 bfA, bfB;
        bfA = *reinterpret_cast<const f16x8*>(Wb);
        #pragma unroll
        for (int ss = 0; ss < 4; ss++) {
            const int s0 = ss * 2, s1 = ss * 2 + 1;
            f16x8 af0[4];
            #pragma unroll
            for (int f = 0; f < 4; f++)
                af0[f] = *reinterpret_cast<const f16x8*>(&R0[abase + f * 16 * LDP + s0 * 32]);
            bfB = *reinterpret_cast<const f16x8*>(Wb + (size_t)s1 * 4096);
            #pragma unroll
            for (int f = 0; f < 4; f++)
                MFMA16(af0[f], bfA, acc[f]);
            f16x8 af1[4];
            #pragma unroll
            for (int f = 0; f < 4; f++)
                af1[f] = *reinterpret_cast<const f16x8*>(&R0[abase + f * 16 * LDP + s1 * 32]);
            if (ss < 3) bfA = *reinterpret_cast<const f16x8*>(Wb + (size_t)(s0 + 2) * 4096);
            #pragma unroll
            for (int f = 0; f < 4; f++)
                MFMA16(af1[f], bfB, acc[f]);
        }
        __syncthreads();
        const float bv = a.bias2[kj * 128 + wid * 16 + l15];
        const int wb = (l4 * 4) * LDP + wid * 16 + l15;
        #pragma unroll
        for (int f = 0; f < 4; f++)
            #pragma unroll
            for (int r = 0; r < 4; r++) {
                float z = acc[f][r] + bv;
                z = z >= 0.f ? z : 0.01f * z;
                R0[wb + (f * 16 + r) * LDP] = f2h(z);
            }
    }
    __syncthreads();

    // ---- stage 3: h4 = leaky(h3 @ w3^T + b3).  N=64, K=128. Waves 2M x 4N.
    {
        const int wm = wid >> 2, wn4 = wid & 3;
        const unsigned short* Wb = a.w3 + (size_t)kj * 8192 + (size_t)wn4 * 512 + lane * 8;
        const int abase3 = (wm * 32 + l15) * LDP + l4 * 8;
        f32x4 acc[2] = {};
        #pragma unroll
        for (int s = 0; s < 4; s++) {
            f16x8 af[2], bf;
            #pragma unroll
            for (int f = 0; f < 2; f++)
                af[f] = *reinterpret_cast<const f16x8*>(&R0[abase3 + f * 16 * LDP + s * 32]);
            bf = *reinterpret_cast<const f16x8*>(Wb + (size_t)s * 2048);
            #pragma unroll
            for (int f = 0; f < 2; f++)
                MFMA16(af[f], bf, acc[f]);
        }
        __syncthreads();
        const float bv = a.bias3[kj * 64 + wn4 * 16 + l15];
        const int wb = (wm * 32 + l4 * 4) * LDP + wn4 * 16 + l15;
        #pragma unroll
        for (int f = 0; f < 2; f++)
            #pragma unroll
            for (int r = 0; r < 4; r++) {
                float z = acc[f][r] + bv;
                z = z >= 0.f ? z : 0.01f * z;
                R0[wb + (f * 16 + r) * LDP] = f2h(z);
            }
    }
    __syncthreads();

    // ---- stage 4: out = h4 @ w4^T + b4 (f32). 384 threads: one (row,o) each.
    if (tid < 384) {
        const int row = tid / 6, o = tid - row * 6;
        float xv[64];
        #pragma unroll
        for (int ch = 0; ch < 8; ch++) {
            s16x8 v = *reinterpret_cast<const s16x8*>(&R0[row * LDP + ch * 8]);
            #pragma unroll
            for (int e = 0; e < 8; e++) xv[ch * 8 + e] = h2f((unsigned short)v[e]);
        }
        const float* w4b = a.w4 + kj * 384 + o * 64;
        float sum = a.bias4[kj * 6 + o];
        #pragma unroll
        for (int i = 0; i < 64; i++) sum = fmaf(xv[i], w4b[i], sum);
        __builtin_nontemporal_store(sum, &a.out[((size_t)(m0 + row) * 80 + kj) * 6 + o]);
    }
}

// ---------------------------------------------------------------------------
extern "C" void kernel_launch(void* const* d_in, const int* in_sizes, int n_in,
                              void* d_out, int out_size, void* d_ws, size_t ws_size,
                              hipStream_t stream)
{
    (void)in_sizes; (void)n_in; (void)out_size; (void)ws_size;
    PrepArgs a;
    a.adj  = (const float*)d_in[2];
    a.v0 = (const float*)d_in[4];  a.g0 = (const float*)d_in[5];  a.b0 = (const float*)d_in[6];
    a.v1 = (const float*)d_in[7];  a.g1 = (const float*)d_in[8];  a.b1 = (const float*)d_in[9];
    a.v2 = (const float*)d_in[10]; a.g2 = (const float*)d_in[11]; a.b2 = (const float*)d_in[12];
    a.v3 = (const float*)d_in[13]; a.g3 = (const float*)d_in[14]; a.b3 = (const float*)d_in[15];
    a.v4 = (const float*)d_in[16]; a.g4 = (const float*)d_in[17]; a.b4 = (const float*)d_in[18];

    char* ws = (char*)d_ws;
    size_t off = 0;
    auto alloc = [&](size_t n) -> void* {
        off = (off + 255) & ~(size_t)255;
        void* p = ws + off;
        off += n;
        return p;
    };
    a.w0 = (unsigned short*)alloc(80ull * 512 * 512 * 2);
    a.w1 = (unsigned short*)alloc(80ull * 256 * 512 * 2);
    a.w2 = (unsigned short*)alloc(80ull * 128 * 256 * 2);
    a.w3 = (unsigned short*)alloc(80ull * 64 * 128 * 2);
    a.w4 = (float*)alloc(80ull * 6 * 64 * 4);
    a.bias0 = (float*)alloc(80ull * 512 * 4);
    a.bias1 = (float*)alloc(80ull * 256 * 4);
    a.bias2 = (float*)alloc(80ull * 128 * 4);
    a.bias3 = (float*)alloc(80ull * 64 * 4);
    a.bias4 = (float*)alloc(80ull * 6 * 4);

    MegaArgs m;
    m.qp   = (const float*)d_in[0];
    m.pf   = (const float*)d_in[1];
    m.Brff = (const float*)d_in[3];
    m.w0 = a.w0; m.w1 = a.w1; m.w2 = a.w2; m.w3 = a.w3; m.w4 = a.w4;
    m.bias0 = a.bias0; m.bias1 = a.bias1; m.bias2 = a.bias2;
    m.bias3 = a.bias3; m.bias4 = a.bias4;
    m.out = (float*)d_out;

    (void)hipFuncSetAttribute((const void*)mega6_kernel,
                              hipFuncAttributeMaxDynamicSharedMemorySize, 66560);

    prep_kernel<<<19320, 256, 0, stream>>>(a);
    mega6_kernel<<<2560, 512, 66560, stream>>>(m);
}

// Round 14
// 311.135 us; speedup vs baseline: 1.0379x; 1.0379x over previous
//
#include <hip/hip_runtime.h>
#include <hip/hip_fp16.h>

#define DI __device__ __forceinline__

typedef __attribute__((ext_vector_type(4))) float f32x4;
typedef __attribute__((ext_vector_type(8))) _Float16 f16x8;
typedef __attribute__((ext_vector_type(8))) short s16x8;

DI unsigned short f2h(float f) { return __half_as_ushort(__float2half(f)); }
DI float h2f(unsigned short u) { return __half2float(__ushort_as_half(u)); }

#define MFMA16(A, B, C) (C) = __builtin_amdgcn_mfma_f32_16x16x32_f16((A), (B), (C), 0, 0, 0)
#define PRIO1 __builtin_amdgcn_s_setprio(1)
#define PRIO0 __builtin_amdgcn_s_setprio(0)

// ---------------------------------------------------------------------------
// Prep: weight-norm fold + diag-scale fold, emitting MFMA-FRAGMENT layout:
//   W'[kj][s][n16][lane(l4*16+l15)][8]; a wave's B-frag load = contiguous 1KB.
// ---------------------------------------------------------------------------
struct PrepArgs {
    const float *adj;
    const float *v0,*g0,*b0,*v1,*g1,*b1,*v2,*g2,*b2,*v3,*g3,*b3,*v4,*g4,*b4;
    unsigned short *w0,*w1,*w2,*w3;
    float *w4, *bias0,*bias1,*bias2,*bias3,*bias4;
};

template <int CIN, int CINPAD>
DI void prep_row(const float* __restrict__ v, const float* __restrict__ g,
                 const float* __restrict__ b, const float* __restrict__ adj,
                 int cout, int use_scale,
                 unsigned short* __restrict__ wout, float* __restrict__ biasout,
                 int ridx, int lane)
{
    const int k = ridx / cout;
    const int o = ridx - k * cout;
    const float* vr = v + (size_t)ridx * CIN;
    float xv[8];
    if (lane * 8 < CIN) {
        const f32x4 p0 = *reinterpret_cast<const f32x4*>(&vr[lane * 8]);
        const f32x4 p1 = *reinterpret_cast<const f32x4*>(&vr[lane * 8 + 4]);
        #pragma unroll
        for (int e = 0; e < 4; e++) { xv[e] = p0[e]; xv[4 + e] = p1[e]; }
    } else {
        #pragma unroll
        for (int e = 0; e < 8; e++) xv[e] = 0.f;
    }
    float ss = 0.f;
    #pragma unroll
    for (int e = 0; e < 8; e++) ss += xv[e] * xv[e];
    #pragma unroll
    for (int off = 32; off >= 1; off >>= 1) ss += __shfl_xor(ss, off, 64);
    float s = g[ridx] / sqrtf(ss);
    float bias = b[ridx];
    if (use_scale) {
        float d = adj[k * 81];            // adj[k][k]
        d = d > 0.f ? d : 0.f;
        s *= d; bias *= d;                // leaky(z)*s == leaky(z*s), s>=0
    }
    if (lane == 0) biasout[ridx] = bias;
    if (lane < CINPAD / 8) {
        unsigned short tmp[8];
        #pragma unroll
        for (int e = 0; e < 8; e++) tmp[e] = f2h(xv[e] * s);
        unsigned short* wj = wout + (size_t)k * cout * CINPAD;
        const int sblk = lane >> 2, l4w = lane & 3;
        const size_t pos = (((size_t)sblk * (cout >> 4) + (o >> 4)) * 64 + l4w * 16 + (o & 15)) * 8;
        *reinterpret_cast<s16x8*>(&wj[pos]) = *reinterpret_cast<const s16x8*>(tmp);
    }
}

DI void prep_w4_row(const float* __restrict__ v, const float* __restrict__ g,
                    const float* __restrict__ b, float* __restrict__ wout,
                    float* __restrict__ biasout, int ridx, int lane)
{
    const float x = v[(size_t)ridx * 64 + lane];
    float ss = x * x;
    #pragma unroll
    for (int off = 32; off >= 1; off >>= 1) ss += __shfl_xor(ss, off, 64);
    const float s = g[ridx] / sqrtf(ss);
    if (lane == 0) biasout[ridx] = b[ridx];
    wout[(size_t)ridx * 64 + lane] = x * s;
}

__global__ __launch_bounds__(256) void prep_kernel(PrepArgs a)
{
    const int bid = blockIdx.x, wave = threadIdx.x >> 6, lane = threadIdx.x & 63;
    if (bid < 10240)      prep_row<480, 512>(a.v0, a.g0, a.b0, a.adj, 512, 1, a.w0, a.bias0, bid * 4 + wave, lane);
    else if (bid < 15360) prep_row<512, 512>(a.v1, a.g1, a.b1, a.adj, 256, 1, a.w1, a.bias1, (bid - 10240) * 4 + wave, lane);
    else if (bid < 17920) prep_row<256, 256>(a.v2, a.g2, a.b2, a.adj, 128, 1, a.w2, a.bias2, (bid - 15360) * 4 + wave, lane);
    else if (bid < 19200) prep_row<128, 128>(a.v3, a.g3, a.b3, a.adj,  64, 0, a.w3, a.bias3, (bid - 17920) * 4 + wave, lane);
    else                  prep_w4_row(a.v4, a.g4, a.b4, a.w4, a.bias4, (bid - 19200) * 4 + wave, lane);
}

// ---------------------------------------------------------------------------
// Mega v7 = mega5 (XOR swizzle, fragment-layout W, 1-step B prefetch) with:
//   - stage 0 K = 480 (15 K-steps; zero-pad and its fill removed)
//   - s_setprio(1) around every MFMA cluster (T5; 2 blocks/CU give diversity)
//   - stage 4 parallelized over 384 threads
// ---------------------------------------------------------------------------
struct MegaArgs {
    const float *qp, *pf, *Brff;
    const unsigned short *w0, *w1, *w2, *w3;
    const float *w4, *bias0, *bias1, *bias2, *bias3, *bias4;
    float* out;
};

__global__ __launch_bounds__(512, 4) void mega7_kernel(MegaArgs a)
{
    extern __shared__ __align__(16) unsigned short R0[];   // 32768 shorts = 64 KB
    const int tid = threadIdx.x, wid = tid >> 6, lane = tid & 63;
    const int l15 = lane & 15, l4 = lane >> 4;
    const int bid = blockIdx.x;
    const int swz = (bid & 7) * 320 + (bid >> 3);   // XCD-chunked, bijective (2560%8==0)
    const int kj = swz >> 5;
    const int m0 = (swz & 31) * 64;

    // ---- prologue: h0 = pf + RFF(qp) -> R0 [64][512] XOR-swizzled, chunks 0..59
    {
        const int row = tid >> 3;                 // 0..63
        const int tq  = tid & 7;
        const int gr  = (m0 + row) * 80 + kj;     // batch-major global row
        const float q0 = a.qp[gr * 3 + 0], q1 = a.qp[gr * 3 + 1], q2 = a.qp[gr * 3 + 2];
        #pragma unroll
        for (int i = 0; i < 8; i++) {
            const int c0 = tq * 8 + i * 64;       // multiples of 8, 0..504
            if (c0 < 480) {
                unsigned short o[8];
                const bool issin = (c0 >= 240);
                const int j0 = issin ? (c0 - 240) : c0;
                const f32x4 b0a = *reinterpret_cast<const f32x4*>(&a.Brff[j0]);
                const f32x4 b0b = *reinterpret_cast<const f32x4*>(&a.Brff[j0 + 4]);
                const f32x4 b1a = *reinterpret_cast<const f32x4*>(&a.Brff[240 + j0]);
                const f32x4 b1b = *reinterpret_cast<const f32x4*>(&a.Brff[240 + j0 + 4]);
                const f32x4 b2a = *reinterpret_cast<const f32x4*>(&a.Brff[480 + j0]);
                const f32x4 b2b = *reinterpret_cast<const f32x4*>(&a.Brff[480 + j0 + 4]);
                const f32x4 p0 = __builtin_nontemporal_load(
                    reinterpret_cast<const f32x4*>(&a.pf[(size_t)gr * 480 + c0]));
                const f32x4 p1 = __builtin_nontemporal_load(
                    reinterpret_cast<const f32x4*>(&a.pf[(size_t)gr * 480 + c0 + 4]));
                #pragma unroll
                for (int e = 0; e < 4; e++) {
                    float rev = q0 * b0a[e] + q1 * b1a[e] + q2 * b2a[e];
                    rev -= floorf(rev);           // v_sin/v_cos take revolutions
                    float t = issin ? __builtin_amdgcn_sinf(rev) : __builtin_amdgcn_cosf(rev);
                    o[e] = f2h(p0[e] + t);
                }
                #pragma unroll
                for (int e = 0; e < 4; e++) {
                    float rev = q0 * b0b[e] + q1 * b1b[e] + q2 * b2b[e];
                    rev -= floorf(rev);
                    float t = issin ? __builtin_amdgcn_sinf(rev) : __builtin_amdgcn_cosf(rev);
                    o[4 + e] = f2h(p1[e] + t);
                }
                const int ck = c0 >> 3;
                *reinterpret_cast<s16x8*>(&R0[row * 512 + ((ck ^ (row & 7)) << 3)]) =
                    *reinterpret_cast<const s16x8*>(o);
            }
        }
    }
    __syncthreads();

    // ---- stage 0: h1 = leaky(h0 @ w0^T + b0).  N=512 (wave owns 64 cols), K=480.
    {
        const unsigned short* Wb = a.w0 + (size_t)kj * 262144 + (size_t)(wid * 4) * 512 + lane * 8;
        f32x4 acc[4][4] = {};
        f16x8 bfA[4], bfB[4];
        #pragma unroll
        for (int g = 0; g < 4; g++) bfA[g] = *reinterpret_cast<const f16x8*>(Wb + g * 512);
        #pragma unroll
        for (int ss = 0; ss < 7; ss++) {          // steps 0..13
            const int s0 = ss * 2, s1 = ss * 2 + 1;
            f16x8 af0[4];
            #pragma unroll
            for (int f = 0; f < 4; f++) {
                const int r = f * 16 + l15;
                af0[f] = *reinterpret_cast<const f16x8*>(&R0[r * 512 + (((s0 * 4 + l4) ^ (r & 7)) << 3)]);
            }
            #pragma unroll
            for (int g = 0; g < 4; g++)
                bfB[g] = *reinterpret_cast<const f16x8*>(Wb + (size_t)s1 * 16384 + g * 512);
            PRIO1;
            #pragma unroll
            for (int f = 0; f < 4; f++)
                #pragma unroll
                for (int g = 0; g < 4; g++)
                    MFMA16(af0[f], bfA[g], acc[f][g]);
            PRIO0;
            f16x8 af1[4];
            #pragma unroll
            for (int f = 0; f < 4; f++) {
                const int r = f * 16 + l15;
                af1[f] = *reinterpret_cast<const f16x8*>(&R0[r * 512 + (((s1 * 4 + l4) ^ (r & 7)) << 3)]);
            }
            #pragma unroll
            for (int g = 0; g < 4; g++)
                bfA[g] = *reinterpret_cast<const f16x8*>(Wb + (size_t)(s0 + 2) * 16384 + g * 512);
            PRIO1;
            #pragma unroll
            for (int f = 0; f < 4; f++)
                #pragma unroll
                for (int g = 0; g < 4; g++)
                    MFMA16(af1[f], bfB[g], acc[f][g]);
            PRIO0;
        }
        {   // tail step s = 14 (bfA already holds it)
            f16x8 af0[4];
            #pragma unroll
            for (int f = 0; f < 4; f++) {
                const int r = f * 16 + l15;
                af0[f] = *reinterpret_cast<const f16x8*>(&R0[r * 512 + (((14 * 4 + l4) ^ (r & 7)) << 3)]);
            }
            PRIO1;
            #pragma unroll
            for (int f = 0; f < 4; f++)
                #pragma unroll
                for (int g = 0; g < 4; g++)
                    MFMA16(af0[f], bfA[g], acc[f][g]);
            PRIO0;
        }
        __syncthreads();                          // all h0 reads done
        float bv[4];
        #pragma unroll
        for (int g = 0; g < 4; g++) bv[g] = a.bias0[kj * 512 + wid * 64 + g * 16 + l15];
        #pragma unroll
        for (int f = 0; f < 4; f++)
            #pragma unroll
            for (int g = 0; g < 4; g++)
                #pragma unroll
                for (int r = 0; r < 4; r++) {
                    float z = acc[f][g][r] + bv[g];
                    z = z >= 0.f ? z : 0.01f * z;
                    const int rr = f * 16 + l4 * 4 + r;
                    const int cc = wid * 64 + g * 16 + l15;
                    R0[rr * 512 + (((cc >> 3) ^ (rr & 7)) << 3) + (cc & 7)] = f2h(z);
                }
    }
    __syncthreads();

    // ---- stage 1: h2 = leaky(h1 @ w1^T + b1).  N=256 (wave owns 32), K=512.
    {
        const unsigned short* Wb = a.w1 + (size_t)kj * 131072 + (size_t)(wid * 2) * 512 + lane * 8;
        f32x4 acc[4][2] = {};
        f16x8 bfA[2], bfB[2];
        #pragma unroll
        for (int g = 0; g < 2; g++) bfA[g] = *reinterpret_cast<const f16x8*>(Wb + g * 512);
        #pragma unroll
        for (int ss = 0; ss < 8; ss++) {
            const int s0 = ss * 2, s1 = ss * 2 + 1;
            f16x8 af0[4];
            #pragma unroll
            for (int f = 0; f < 4; f++) {
                const int r = f * 16 + l15;
                af0[f] = *reinterpret_cast<const f16x8*>(&R0[r * 512 + (((s0 * 4 + l4) ^ (r & 7)) << 3)]);
            }
            #pragma unroll
            for (int g = 0; g < 2; g++)
                bfB[g] = *reinterpret_cast<const f16x8*>(Wb + (size_t)s1 * 8192 + g * 512);
            PRIO1;
            #pragma unroll
            for (int f = 0; f < 4; f++)
                #pragma unroll
                for (int g = 0; g < 2; g++)
                    MFMA16(af0[f], bfA[g], acc[f][g]);
            PRIO0;
            f16x8 af1[4];
            #pragma unroll
            for (int f = 0; f < 4; f++) {
                const int r = f * 16 + l15;
                af1[f] = *reinterpret_cast<const f16x8*>(&R0[r * 512 + (((s1 * 4 + l4) ^ (r & 7)) << 3)]);
            }
            if (ss < 7) {
                #pragma unroll
                for (int g = 0; g < 2; g++)
                    bfA[g] = *reinterpret_cast<const f16x8*>(Wb + (size_t)(s0 + 2) * 8192 + g * 512);
            }
            PRIO1;
            #pragma unroll
            for (int f = 0; f < 4; f++)
                #pragma unroll
                for (int g = 0; g < 2; g++)
                    MFMA16(af1[f], bfB[g], acc[f][g]);
            PRIO0;
        }
        __syncthreads();
        float bv[2];
        #pragma unroll
        for (int g = 0; g < 2; g++) bv[g] = a.bias1[kj * 256 + wid * 32 + g * 16 + l15];
        #pragma unroll
        for (int f = 0; f < 4; f++)
            #pragma unroll
            for (int g = 0; g < 2; g++)
                #pragma unroll
                for (int r = 0; r < 4; r++) {
                    float z = acc[f][g][r] + bv[g];
                    z = z >= 0.f ? z : 0.01f * z;
                    const int rr = f * 16 + l4 * 4 + r;
                    const int cc = wid * 32 + g * 16 + l15;
                    R0[rr * 256 + (((cc >> 3) ^ (rr & 7)) << 3) + (cc & 7)] = f2h(z);
                }
    }
    __syncthreads();

    // ---- stage 2: h3 = leaky(h2 @ w2^T + b2).  N=128 (wave owns 16), K=256.
    {
        const unsigned short* Wb = a.w2 + (size_t)kj * 32768 + (size_t)wid * 512 + lane * 8;
        f32x4 acc[4] = {};
        f16x8 bfA, bfB;
        bfA = *reinterpret_cast<const f16x8*>(Wb);
        #pragma unroll
        for (int ss = 0; ss < 4; ss++) {
            const int s0 = ss * 2, s1 = ss * 2 + 1;
            f16x8 af0[4];
            #pragma unroll
            for (int f = 0; f < 4; f++) {
                const int r = f * 16 + l15;
                af0[f] = *reinterpret_cast<const f16x8*>(&R0[r * 256 + (((s0 * 4 + l4) ^ (r & 7)) << 3)]);
            }
            bfB = *reinterpret_cast<const f16x8*>(Wb + (size_t)s1 * 4096);
            PRIO1;
            #pragma unroll
            for (int f = 0; f < 4; f++)
                MFMA16(af0[f], bfA, acc[f]);
            PRIO0;
            f16x8 af1[4];
            #pragma unroll
            for (int f = 0; f < 4; f++) {
                const int r = f * 16 + l15;
                af1[f] = *reinterpret_cast<const f16x8*>(&R0[r * 256 + (((s1 * 4 + l4) ^ (r & 7)) << 3)]);
            }
            if (ss < 3) bfA = *reinterpret_cast<const f16x8*>(Wb + (size_t)(s0 + 2) * 4096);
            PRIO1;
            #pragma unroll
            for (int f = 0; f < 4; f++)
                MFMA16(af1[f], bfB, acc[f]);
            PRIO0;
        }
        __syncthreads();
        const float bv = a.bias2[kj * 128 + wid * 16 + l15];
        #pragma unroll
        for (int f = 0; f < 4; f++)
            #pragma unroll
            for (int r = 0; r < 4; r++) {
                float z = acc[f][r] + bv;
                z = z >= 0.f ? z : 0.01f * z;
                const int rr = f * 16 + l4 * 4 + r;
                const int cc = wid * 16 + l15;
                R0[rr * 128 + (((cc >> 3) ^ (rr & 7)) << 3) + (cc & 7)] = f2h(z);
            }
    }
    __syncthreads();

    // ---- stage 3: h4 = leaky(h3 @ w3^T + b3).  N=64, K=128. Waves 2M x 4N.
    {
        const int wm = wid >> 2, wn4 = wid & 3;
        const unsigned short* Wb = a.w3 + (size_t)kj * 8192 + (size_t)wn4 * 512 + lane * 8;
        f32x4 acc[2] = {};
        #pragma unroll
        for (int s = 0; s < 4; s++) {
            f16x8 af[2], bf;
            #pragma unroll
            for (int f = 0; f < 2; f++) {
                const int r = wm * 32 + f * 16 + l15;
                af[f] = *reinterpret_cast<const f16x8*>(&R0[r * 128 + (((s * 4 + l4) ^ (r & 7)) << 3)]);
            }
            bf = *reinterpret_cast<const f16x8*>(Wb + (size_t)s * 2048);
            PRIO1;
            #pragma unroll
            for (int f = 0; f < 2; f++)
                MFMA16(af[f], bf, acc[f]);
            PRIO0;
        }
        __syncthreads();
        const float bv = a.bias3[kj * 64 + wn4 * 16 + l15];
        #pragma unroll
        for (int f = 0; f < 2; f++)
            #pragma unroll
            for (int r = 0; r < 4; r++) {
                float z = acc[f][r] + bv;
                z = z >= 0.f ? z : 0.01f * z;
                const int rr = wm * 32 + f * 16 + l4 * 4 + r;
                const int cc = wn4 * 16 + l15;
                R0[rr * 64 + (((cc >> 3) ^ (rr & 7)) << 3) + (cc & 7)] = f2h(z);
            }
    }
    __syncthreads();

    // ---- stage 4: out = h4 @ w4^T + b4 (f32). 384 threads: one (row,o) each.
    if (tid < 384) {
        const int row = tid / 6, o = tid - row * 6;
        float xv[64];
        #pragma unroll
        for (int ch = 0; ch < 8; ch++) {
            s16x8 v = *reinterpret_cast<const s16x8*>(&R0[row * 64 + ((ch ^ (row & 7)) << 3)]);
            #pragma unroll
            for (int e = 0; e < 8; e++) xv[ch * 8 + e] = h2f((unsigned short)v[e]);
        }
        const float* w4b = a.w4 + kj * 384 + o * 64;
        float sum = a.bias4[kj * 6 + o];
        #pragma unroll
        for (int i = 0; i < 64; i++) sum = fmaf(xv[i], w4b[i], sum);
        __builtin_nontemporal_store(sum, &a.out[((size_t)(m0 + row) * 80 + kj) * 6 + o]);
    }
}

// ---------------------------------------------------------------------------
extern "C" void kernel_launch(void* const* d_in, const int* in_sizes, int n_in,
                              void* d_out, int out_size, void* d_ws, size_t ws_size,
                              hipStream_t stream)
{
    (void)in_sizes; (void)n_in; (void)out_size; (void)ws_size;
    PrepArgs a;
    a.adj  = (const float*)d_in[2];
    a.v0 = (const float*)d_in[4];  a.g0 = (const float*)d_in[5];  a.b0 = (const float*)d_in[6];
    a.v1 = (const float*)d_in[7];  a.g1 = (const float*)d_in[8];  a.b1 = (const float*)d_in[9];
    a.v2 = (const float*)d_in[10]; a.g2 = (const float*)d_in[11]; a.b2 = (const float*)d_in[12];
    a.v3 = (const float*)d_in[13]; a.g3 = (const float*)d_in[14]; a.b3 = (const float*)d_in[15];
    a.v4 = (const float*)d_in[16]; a.g4 = (const float*)d_in[17]; a.b4 = (const float*)d_in[18];

    char* ws = (char*)d_ws;
    size_t off = 0;
    auto alloc = [&](size_t n) -> void* {
        off = (off + 255) & ~(size_t)255;
        void* p = ws + off;
        off += n;
        return p;
    };
    a.w0 = (unsigned short*)alloc(80ull * 512 * 512 * 2);
    a.w1 = (unsigned short*)alloc(80ull * 256 * 512 * 2);
    a.w2 = (unsigned short*)alloc(80ull * 128 * 256 * 2);
    a.w3 = (unsigned short*)alloc(80ull * 64 * 128 * 2);
    a.w4 = (float*)alloc(80ull * 6 * 64 * 4);
    a.bias0 = (float*)alloc(80ull * 512 * 4);
    a.bias1 = (float*)alloc(80ull * 256 * 4);
    a.bias2 = (float*)alloc(80ull * 128 * 4);
    a.bias3 = (float*)alloc(80ull * 64 * 4);
    a.bias4 = (float*)alloc(80ull * 6 * 4);

    MegaArgs m;
    m.qp   = (const float*)d_in[0];
    m.pf   = (const float*)d_in[1];
    m.Brff = (const float*)d_in[3];
    m.w0 = a.w0; m.w1 = a.w1; m.w2 = a.w2; m.w3 = a.w3; m.w4 = a.w4;
    m.bias0 = a.bias0; m.bias1 = a.bias1; m.bias2 = a.bias2;
    m.bias3 = a.bias3; m.bias4 = a.bias4;
    m.out = (float*)d_out;

    (void)hipFuncSetAttribute((const void*)mega7_kernel,
                              hipFuncAttributeMaxDynamicSharedMemorySize, 65536);

    prep_kernel<<<19320, 256, 0, stream>>>(a);
    mega7_kernel<<<2560, 512, 65536, stream>>>(m);
}

// Round 15
// 282.573 us; speedup vs baseline: 1.1428x; 1.1011x over previous
//
#include <hip/hip_runtime.h>
#include <hip/hip_fp16.h>

#define DI __device__ __forceinline__

typedef __attribute__((ext_vector_type(4))) float f32x4;
typedef __attribute__((ext_vector_type(8))) _Float16 f16x8;
typedef __attribute__((ext_vector_type(8))) short s16x8;

DI unsigned short f2h(float f) { return __half_as_ushort(__float2half(f)); }
DI float h2f(unsigned short u) { return __half2float(__ushort_as_half(u)); }

#define MFMA16(A, B, C) (C) = __builtin_amdgcn_mfma_f32_16x16x32_f16((A), (B), (C), 0, 0, 0)

// ---------------------------------------------------------------------------
// Prep: weight-norm fold + diag-scale fold, emitting MFMA-FRAGMENT layout:
//   W'[kj][s][n16][lane(l4*16+l15)][8]; a wave's B-frag load = contiguous 1KB.
// ---------------------------------------------------------------------------
struct PrepArgs {
    const float *adj;
    const float *v0,*g0,*b0,*v1,*g1,*b1,*v2,*g2,*b2,*v3,*g3,*b3,*v4,*g4,*b4;
    unsigned short *w0,*w1,*w2,*w3;
    float *w4, *bias0,*bias1,*bias2,*bias3,*bias4;
};

template <int CIN, int CINPAD>
DI void prep_row(const float* __restrict__ v, const float* __restrict__ g,
                 const float* __restrict__ b, const float* __restrict__ adj,
                 int cout, int use_scale,
                 unsigned short* __restrict__ wout, float* __restrict__ biasout,
                 int ridx, int lane)
{
    const int k = ridx / cout;
    const int o = ridx - k * cout;
    const float* vr = v + (size_t)ridx * CIN;
    float xv[8];
    if (lane * 8 < CIN) {
        const f32x4 p0 = *reinterpret_cast<const f32x4*>(&vr[lane * 8]);
        const f32x4 p1 = *reinterpret_cast<const f32x4*>(&vr[lane * 8 + 4]);
        #pragma unroll
        for (int e = 0; e < 4; e++) { xv[e] = p0[e]; xv[4 + e] = p1[e]; }
    } else {
        #pragma unroll
        for (int e = 0; e < 8; e++) xv[e] = 0.f;
    }
    float ss = 0.f;
    #pragma unroll
    for (int e = 0; e < 8; e++) ss += xv[e] * xv[e];
    #pragma unroll
    for (int off = 32; off >= 1; off >>= 1) ss += __shfl_xor(ss, off, 64);
    float s = g[ridx] / sqrtf(ss);
    float bias = b[ridx];
    if (use_scale) {
        float d = adj[k * 81];            // adj[k][k]
        d = d > 0.f ? d : 0.f;
        s *= d; bias *= d;                // leaky(z)*s == leaky(z*s), s>=0
    }
    if (lane == 0) biasout[ridx] = bias;
    if (lane < CINPAD / 8) {
        unsigned short tmp[8];
        #pragma unroll
        for (int e = 0; e < 8; e++) tmp[e] = f2h(xv[e] * s);
        unsigned short* wj = wout + (size_t)k * cout * CINPAD;
        const int sblk = lane >> 2, l4w = lane & 3;
        const size_t pos = (((size_t)sblk * (cout >> 4) + (o >> 4)) * 64 + l4w * 16 + (o & 15)) * 8;
        *reinterpret_cast<s16x8*>(&wj[pos]) = *reinterpret_cast<const s16x8*>(tmp);
    }
}

DI void prep_w4_row(const float* __restrict__ v, const float* __restrict__ g,
                    const float* __restrict__ b, float* __restrict__ wout,
                    float* __restrict__ biasout, int ridx, int lane)
{
    const float x = v[(size_t)ridx * 64 + lane];
    float ss = x * x;
    #pragma unroll
    for (int off = 32; off >= 1; off >>= 1) ss += __shfl_xor(ss, off, 64);
    const float s = g[ridx] / sqrtf(ss);
    if (lane == 0) biasout[ridx] = b[ridx];
    wout[(size_t)ridx * 64 + lane] = x * s;
}

__global__ __launch_bounds__(256) void prep_kernel(PrepArgs a)
{
    const int bid = blockIdx.x, wave = threadIdx.x >> 6, lane = threadIdx.x & 63;
    if (bid < 10240)      prep_row<480, 512>(a.v0, a.g0, a.b0, a.adj, 512, 1, a.w0, a.bias0, bid * 4 + wave, lane);
    else if (bid < 15360) prep_row<512, 512>(a.v1, a.g1, a.b1, a.adj, 256, 1, a.w1, a.bias1, (bid - 10240) * 4 + wave, lane);
    else if (bid < 17920) prep_row<256, 256>(a.v2, a.g2, a.b2, a.adj, 128, 1, a.w2, a.bias2, (bid - 15360) * 4 + wave, lane);
    else if (bid < 19200) prep_row<128, 128>(a.v3, a.g3, a.b3, a.adj,  64, 0, a.w3, a.bias3, (bid - 17920) * 4 + wave, lane);
    else                  prep_w4_row(a.v4, a.g4, a.b4, a.w4, a.bias4, (bid - 19200) * 4 + wave, lane);
}

// ---------------------------------------------------------------------------
// Mega v5 (round-12 verified best): one block = 64 batch rows of one joint,
// 512 threads, single 64 KB in-place h-buffer (XOR chunk swizzle), fragment-
// layout W so every B load is a wave-coalesced 1KB read, 1-step B prefetch,
// fused RFF prologue, NT loads for pf.
// ---------------------------------------------------------------------------
struct MegaArgs {
    const float *qp, *pf, *Brff;
    const unsigned short *w0, *w1, *w2, *w3;
    const float *w4, *bias0, *bias1, *bias2, *bias3, *bias4;
    float* out;
};

__global__ __launch_bounds__(512, 4) void mega5_kernel(MegaArgs a)
{
    extern __shared__ __align__(16) unsigned short R0[];   // 32768 shorts = 64 KB
    const int tid = threadIdx.x, wid = tid >> 6, lane = tid & 63;
    const int l15 = lane & 15, l4 = lane >> 4;
    const int bid = blockIdx.x;
    const int swz = (bid & 7) * 320 + (bid >> 3);   // XCD-chunked, bijective (2560%8==0)
    const int kj = swz >> 5;
    const int m0 = (swz & 31) * 64;

    // ---- prologue: h0 = pf + RFF(qp)  -> R0 as [64][512] (480 real + 32 zero-pad)
    {
        const int row = tid >> 3;                 // 0..63
        const int tq  = tid & 7;
        const int gr  = (m0 + row) * 80 + kj;     // batch-major global row
        const float q0 = a.qp[gr * 3 + 0], q1 = a.qp[gr * 3 + 1], q2 = a.qp[gr * 3 + 2];
        #pragma unroll
        for (int i = 0; i < 8; i++) {
            const int c0 = tq * 8 + i * 64;       // multiples of 8, 0..504
            unsigned short o[8];
            if (c0 < 480) {
                const bool issin = (c0 >= 240);
                const int j0 = issin ? (c0 - 240) : c0;
                const f32x4 b0a = *reinterpret_cast<const f32x4*>(&a.Brff[j0]);
                const f32x4 b0b = *reinterpret_cast<const f32x4*>(&a.Brff[j0 + 4]);
                const f32x4 b1a = *reinterpret_cast<const f32x4*>(&a.Brff[240 + j0]);
                const f32x4 b1b = *reinterpret_cast<const f32x4*>(&a.Brff[240 + j0 + 4]);
                const f32x4 b2a = *reinterpret_cast<const f32x4*>(&a.Brff[480 + j0]);
                const f32x4 b2b = *reinterpret_cast<const f32x4*>(&a.Brff[480 + j0 + 4]);
                const f32x4 p0 = __builtin_nontemporal_load(
                    reinterpret_cast<const f32x4*>(&a.pf[(size_t)gr * 480 + c0]));
                const f32x4 p1 = __builtin_nontemporal_load(
                    reinterpret_cast<const f32x4*>(&a.pf[(size_t)gr * 480 + c0 + 4]));
                #pragma unroll
                for (int e = 0; e < 4; e++) {
                    float rev = q0 * b0a[e] + q1 * b1a[e] + q2 * b2a[e];
                    rev -= floorf(rev);           // v_sin/v_cos take revolutions
                    float t = issin ? __builtin_amdgcn_sinf(rev) : __builtin_amdgcn_cosf(rev);
                    o[e] = f2h(p0[e] + t);
                }
                #pragma unroll
                for (int e = 0; e < 4; e++) {
                    float rev = q0 * b0b[e] + q1 * b1b[e] + q2 * b2b[e];
                    rev -= floorf(rev);
                    float t = issin ? __builtin_amdgcn_sinf(rev) : __builtin_amdgcn_cosf(rev);
                    o[4 + e] = f2h(p1[e] + t);
                }
            } else {
                #pragma unroll
                for (int e = 0; e < 8; e++) o[e] = 0;
            }
            const int ck = c0 >> 3;
            *reinterpret_cast<s16x8*>(&R0[row * 512 + ((ck ^ (row & 7)) << 3)]) =
                *reinterpret_cast<const s16x8*>(o);
        }
    }
    __syncthreads();

    // ---- stage 0: h1 = leaky(h0 @ w0^T + b0).  N=512 (wave owns 64 cols), K=512.
    {
        const unsigned short* Wb = a.w0 + (size_t)kj * 262144 + (size_t)(wid * 4) * 512 + lane * 8;
        f32x4 acc[4][4] = {};
        f16x8 bfA[4], bfB[4];
        #pragma unroll
        for (int g = 0; g < 4; g++) bfA[g] = *reinterpret_cast<const f16x8*>(Wb + g * 512);
        #pragma unroll
        for (int ss = 0; ss < 8; ss++) {
            const int s0 = ss * 2, s1 = ss * 2 + 1;
            f16x8 af0[4];
            #pragma unroll
            for (int f = 0; f < 4; f++) {
                const int r = f * 16 + l15;
                af0[f] = *reinterpret_cast<const f16x8*>(&R0[r * 512 + (((s0 * 4 + l4) ^ (r & 7)) << 3)]);
            }
            #pragma unroll
            for (int g = 0; g < 4; g++)
                bfB[g] = *reinterpret_cast<const f16x8*>(Wb + (size_t)s1 * 16384 + g * 512);
            #pragma unroll
            for (int f = 0; f < 4; f++)
                #pragma unroll
                for (int g = 0; g < 4; g++)
                    MFMA16(af0[f], bfA[g], acc[f][g]);
            f16x8 af1[4];
            #pragma unroll
            for (int f = 0; f < 4; f++) {
                const int r = f * 16 + l15;
                af1[f] = *reinterpret_cast<const f16x8*>(&R0[r * 512 + (((s1 * 4 + l4) ^ (r & 7)) << 3)]);
            }
            if (ss < 7) {
                #pragma unroll
                for (int g = 0; g < 4; g++)
                    bfA[g] = *reinterpret_cast<const f16x8*>(Wb + (size_t)(s0 + 2) * 16384 + g * 512);
            }
            #pragma unroll
            for (int f = 0; f < 4; f++)
                #pragma unroll
                for (int g = 0; g < 4; g++)
                    MFMA16(af1[f], bfB[g], acc[f][g]);
        }
        __syncthreads();                          // all h0 reads done
        float bv[4];
        #pragma unroll
        for (int g = 0; g < 4; g++) bv[g] = a.bias0[kj * 512 + wid * 64 + g * 16 + l15];
        #pragma unroll
        for (int f = 0; f < 4; f++)
            #pragma unroll
            for (int g = 0; g < 4; g++)
                #pragma unroll
                for (int r = 0; r < 4; r++) {
                    float z = acc[f][g][r] + bv[g];
                    z = z >= 0.f ? z : 0.01f * z;
                    const int rr = f * 16 + l4 * 4 + r;
                    const int cc = wid * 64 + g * 16 + l15;
                    R0[rr * 512 + (((cc >> 3) ^ (rr & 7)) << 3) + (cc & 7)] = f2h(z);
                }
    }
    __syncthreads();

    // ---- stage 1: h2 = leaky(h1 @ w1^T + b1).  N=256 (wave owns 32), K=512.
    {
        const unsigned short* Wb = a.w1 + (size_t)kj * 131072 + (size_t)(wid * 2) * 512 + lane * 8;
        f32x4 acc[4][2] = {};
        f16x8 bfA[2], bfB[2];
        #pragma unroll
        for (int g = 0; g < 2; g++) bfA[g] = *reinterpret_cast<const f16x8*>(Wb + g * 512);
        #pragma unroll
        for (int ss = 0; ss < 8; ss++) {
            const int s0 = ss * 2, s1 = ss * 2 + 1;
            f16x8 af0[4];
            #pragma unroll
            for (int f = 0; f < 4; f++) {
                const int r = f * 16 + l15;
                af0[f] = *reinterpret_cast<const f16x8*>(&R0[r * 512 + (((s0 * 4 + l4) ^ (r & 7)) << 3)]);
            }
            #pragma unroll
            for (int g = 0; g < 2; g++)
                bfB[g] = *reinterpret_cast<const f16x8*>(Wb + (size_t)s1 * 8192 + g * 512);
            #pragma unroll
            for (int f = 0; f < 4; f++)
                #pragma unroll
                for (int g = 0; g < 2; g++)
                    MFMA16(af0[f], bfA[g], acc[f][g]);
            f16x8 af1[4];
            #pragma unroll
            for (int f = 0; f < 4; f++) {
                const int r = f * 16 + l15;
                af1[f] = *reinterpret_cast<const f16x8*>(&R0[r * 512 + (((s1 * 4 + l4) ^ (r & 7)) << 3)]);
            }
            if (ss < 7) {
                #pragma unroll
                for (int g = 0; g < 2; g++)
                    bfA[g] = *reinterpret_cast<const f16x8*>(Wb + (size_t)(s0 + 2) * 8192 + g * 512);
            }
            #pragma unroll
            for (int f = 0; f < 4; f++)
                #pragma unroll
                for (int g = 0; g < 2; g++)
                    MFMA16(af1[f], bfB[g], acc[f][g]);
        }
        __syncthreads();
        float bv[2];
        #pragma unroll
        for (int g = 0; g < 2; g++) bv[g] = a.bias1[kj * 256 + wid * 32 + g * 16 + l15];
        #pragma unroll
        for (int f = 0; f < 4; f++)
            #pragma unroll
            for (int g = 0; g < 2; g++)
                #pragma unroll
                for (int r = 0; r < 4; r++) {
                    float z = acc[f][g][r] + bv[g];
                    z = z >= 0.f ? z : 0.01f * z;
                    const int rr = f * 16 + l4 * 4 + r;
                    const int cc = wid * 32 + g * 16 + l15;
                    R0[rr * 256 + (((cc >> 3) ^ (rr & 7)) << 3) + (cc & 7)] = f2h(z);
                }
    }
    __syncthreads();

    // ---- stage 2: h3 = leaky(h2 @ w2^T + b2).  N=128 (wave owns 16), K=256.
    {
        const unsigned short* Wb = a.w2 + (size_t)kj * 32768 + (size_t)wid * 512 + lane * 8;
        f32x4 acc[4] = {};
        f16x8 bfA, bfB;
        bfA = *reinterpret_cast<const f16x8*>(Wb);
        #pragma unroll
        for (int ss = 0; ss < 4; ss++) {
            const int s0 = ss * 2, s1 = ss * 2 + 1;
            f16x8 af0[4];
            #pragma unroll
            for (int f = 0; f < 4; f++) {
                const int r = f * 16 + l15;
                af0[f] = *reinterpret_cast<const f16x8*>(&R0[r * 256 + (((s0 * 4 + l4) ^ (r & 7)) << 3)]);
            }
            bfB = *reinterpret_cast<const f16x8*>(Wb + (size_t)s1 * 4096);
            #pragma unroll
            for (int f = 0; f < 4; f++)
                MFMA16(af0[f], bfA, acc[f]);
            f16x8 af1[4];
            #pragma unroll
            for (int f = 0; f < 4; f++) {
                const int r = f * 16 + l15;
                af1[f] = *reinterpret_cast<const f16x8*>(&R0[r * 256 + (((s1 * 4 + l4) ^ (r & 7)) << 3)]);
            }
            if (ss < 3) bfA = *reinterpret_cast<const f16x8*>(Wb + (size_t)(s0 + 2) * 4096);
            #pragma unroll
            for (int f = 0; f < 4; f++)
                MFMA16(af1[f], bfB, acc[f]);
        }
        __syncthreads();
        const float bv = a.bias2[kj * 128 + wid * 16 + l15];
        #pragma unroll
        for (int f = 0; f < 4; f++)
            #pragma unroll
            for (int r = 0; r < 4; r++) {
                float z = acc[f][r] + bv;
                z = z >= 0.f ? z : 0.01f * z;
                const int rr = f * 16 + l4 * 4 + r;
                const int cc = wid * 16 + l15;
                R0[rr * 128 + (((cc >> 3) ^ (rr & 7)) << 3) + (cc & 7)] = f2h(z);
            }
    }
    __syncthreads();

    // ---- stage 3: h4 = leaky(h3 @ w3^T + b3).  N=64, K=128. Waves 2M x 4N.
    {
        const int wm = wid >> 2, wn4 = wid & 3;
        const unsigned short* Wb = a.w3 + (size_t)kj * 8192 + (size_t)wn4 * 512 + lane * 8;
        f32x4 acc[2] = {};
        #pragma unroll
        for (int s = 0; s < 4; s++) {
            f16x8 af[2], bf;
            #pragma unroll
            for (int f = 0; f < 2; f++) {
                const int r = wm * 32 + f * 16 + l15;
                af[f] = *reinterpret_cast<const f16x8*>(&R0[r * 128 + (((s * 4 + l4) ^ (r & 7)) << 3)]);
            }
            bf = *reinterpret_cast<const f16x8*>(Wb + (size_t)s * 2048);
            #pragma unroll
            for (int f = 0; f < 2; f++)
                MFMA16(af[f], bf, acc[f]);
        }
        __syncthreads();
        const float bv = a.bias3[kj * 64 + wn4 * 16 + l15];
        #pragma unroll
        for (int f = 0; f < 2; f++)
            #pragma unroll
            for (int r = 0; r < 4; r++) {
                float z = acc[f][r] + bv;
                z = z >= 0.f ? z : 0.01f * z;
                const int rr = wm * 32 + f * 16 + l4 * 4 + r;
                const int cc = wn4 * 16 + l15;
                R0[rr * 64 + (((cc >> 3) ^ (rr & 7)) << 3) + (cc & 7)] = f2h(z);
            }
    }
    __syncthreads();

    // ---- stage 4: out = h4 @ w4^T + b4 (f32, 6 outputs per row, NT stores).
    if (tid < 64) {
        const int row = tid;
        float xv[64];
        #pragma unroll
        for (int ch = 0; ch < 8; ch++) {
            s16x8 v = *reinterpret_cast<const s16x8*>(&R0[row * 64 + ((ch ^ (row & 7)) << 3)]);
            #pragma unroll
            for (int e = 0; e < 8; e++) xv[ch * 8 + e] = h2f((unsigned short)v[e]);
        }
        const float* w4b = a.w4 + kj * 384;
        float* op = a.out + ((size_t)(m0 + row) * 80 + kj) * 6;
        #pragma unroll
        for (int o = 0; o < 6; o++) {
            float sum = a.bias4[kj * 6 + o];
            #pragma unroll
            for (int i = 0; i < 64; i++) sum = fmaf(xv[i], w4b[o * 64 + i], sum);
            __builtin_nontemporal_store(sum, &op[o]);
        }
    }
}

// ---------------------------------------------------------------------------
extern "C" void kernel_launch(void* const* d_in, const int* in_sizes, int n_in,
                              void* d_out, int out_size, void* d_ws, size_t ws_size,
                              hipStream_t stream)
{
    (void)in_sizes; (void)n_in; (void)out_size; (void)ws_size;
    PrepArgs a;
    a.adj  = (const float*)d_in[2];
    a.v0 = (const float*)d_in[4];  a.g0 = (const float*)d_in[5];  a.b0 = (const float*)d_in[6];
    a.v1 = (const float*)d_in[7];  a.g1 = (const float*)d_in[8];  a.b1 = (const float*)d_in[9];
    a.v2 = (const float*)d_in[10]; a.g2 = (const float*)d_in[11]; a.b2 = (const float*)d_in[12];
    a.v3 = (const float*)d_in[13]; a.g3 = (const float*)d_in[14]; a.b3 = (const float*)d_in[15];
    a.v4 = (const float*)d_in[16]; a.g4 = (const float*)d_in[17]; a.b4 = (const float*)d_in[18];

    char* ws = (char*)d_ws;
    size_t off = 0;
    auto alloc = [&](size_t n) -> void* {
        off = (off + 255) & ~(size_t)255;
        void* p = ws + off;
        off += n;
        return p;
    };
    a.w0 = (unsigned short*)alloc(80ull * 512 * 512 * 2);
    a.w1 = (unsigned short*)alloc(80ull * 256 * 512 * 2);
    a.w2 = (unsigned short*)alloc(80ull * 128 * 256 * 2);
    a.w3 = (unsigned short*)alloc(80ull * 64 * 128 * 2);
    a.w4 = (float*)alloc(80ull * 6 * 64 * 4);
    a.bias0 = (float*)alloc(80ull * 512 * 4);
    a.bias1 = (float*)alloc(80ull * 256 * 4);
    a.bias2 = (float*)alloc(80ull * 128 * 4);
    a.bias3 = (float*)alloc(80ull * 64 * 4);
    a.bias4 = (float*)alloc(80ull * 6 * 4);

    MegaArgs m;
    m.qp   = (const float*)d_in[0];
    m.pf   = (const float*)d_in[1];
    m.Brff = (const float*)d_in[3];
    m.w0 = a.w0; m.w1 = a.w1; m.w2 = a.w2; m.w3 = a.w3; m.w4 = a.w4;
    m.bias0 = a.bias0; m.bias1 = a.bias1; m.bias2 = a.bias2;
    m.bias3 = a.bias3; m.bias4 = a.bias4;
    m.out = (float*)d_out;

    (void)hipFuncSetAttribute((const void*)mega5_kernel,
                              hipFuncAttributeMaxDynamicSharedMemorySize, 65536);

    prep_kernel<<<19320, 256, 0, stream>>>(a);
    mega5_kernel<<<2560, 512, 65536, stream>>>(m);
}

// Round 16
// 280.535 us; speedup vs baseline: 1.1511x; 1.0073x over previous
//
#include <hip/hip_runtime.h>
#include <hip/hip_fp16.h>

#define DI __device__ __forceinline__

typedef __attribute__((ext_vector_type(4))) float f32x4;
typedef __attribute__((ext_vector_type(8))) _Float16 f16x8;
typedef __attribute__((ext_vector_type(8))) short s16x8;
typedef __attribute__((ext_vector_type(4))) short s16x4;

DI unsigned short f2h(float f) { return __half_as_ushort(__float2half(f)); }
DI float h2f(unsigned short u) { return __half2float(__ushort_as_half(u)); }

// operand-swapped: A-operand = weight fragment, B-operand = activation fragment.
// D[o][row]: lane holds o = l4*4+r (4 consecutive channels), row = l15.
#define MFMA16(A, B, C) (C) = __builtin_amdgcn_mfma_f32_16x16x32_f16((A), (B), (C), 0, 0, 0)

// ---------------------------------------------------------------------------
// Prep: weight-norm fold + diag-scale fold, emitting MFMA-FRAGMENT layout:
//   W'[kj][s][n16][lane(l4*16+l15)][8]; a wave's W-frag load = contiguous 1KB.
// ---------------------------------------------------------------------------
struct PrepArgs {
    const float *adj;
    const float *v0,*g0,*b0,*v1,*g1,*b1,*v2,*g2,*b2,*v3,*g3,*b3,*v4,*g4,*b4;
    unsigned short *w0,*w1,*w2,*w3;
    float *w4, *bias0,*bias1,*bias2,*bias3,*bias4;
};

template <int CIN, int CINPAD>
DI void prep_row(const float* __restrict__ v, const float* __restrict__ g,
                 const float* __restrict__ b, const float* __restrict__ adj,
                 int cout, int use_scale,
                 unsigned short* __restrict__ wout, float* __restrict__ biasout,
                 int ridx, int lane)
{
    const int k = ridx / cout;
    const int o = ridx - k * cout;
    const float* vr = v + (size_t)ridx * CIN;
    float xv[8];
    if (lane * 8 < CIN) {
        const f32x4 p0 = *reinterpret_cast<const f32x4*>(&vr[lane * 8]);
        const f32x4 p1 = *reinterpret_cast<const f32x4*>(&vr[lane * 8 + 4]);
        #pragma unroll
        for (int e = 0; e < 4; e++) { xv[e] = p0[e]; xv[4 + e] = p1[e]; }
    } else {
        #pragma unroll
        for (int e = 0; e < 8; e++) xv[e] = 0.f;
    }
    float ss = 0.f;
    #pragma unroll
    for (int e = 0; e < 8; e++) ss += xv[e] * xv[e];
    #pragma unroll
    for (int off = 32; off >= 1; off >>= 1) ss += __shfl_xor(ss, off, 64);
    float s = g[ridx] / sqrtf(ss);
    float bias = b[ridx];
    if (use_scale) {
        float d = adj[k * 81];            // adj[k][k]
        d = d > 0.f ? d : 0.f;
        s *= d; bias *= d;                // leaky(z)*s == leaky(z*s), s>=0
    }
    if (lane == 0) biasout[ridx] = bias;
    if (lane < CINPAD / 8) {
        unsigned short tmp[8];
        #pragma unroll
        for (int e = 0; e < 8; e++) tmp[e] = f2h(xv[e] * s);
        unsigned short* wj = wout + (size_t)k * cout * CINPAD;
        const int sblk = lane >> 2, l4w = lane & 3;
        const size_t pos = (((size_t)sblk * (cout >> 4) + (o >> 4)) * 64 + l4w * 16 + (o & 15)) * 8;
        *reinterpret_cast<s16x8*>(&wj[pos]) = *reinterpret_cast<const s16x8*>(tmp);
    }
}

DI void prep_w4_row(const float* __restrict__ v, const float* __restrict__ g,
                    const float* __restrict__ b, float* __restrict__ wout,
                    float* __restrict__ biasout, int ridx, int lane)
{
    const float x = v[(size_t)ridx * 64 + lane];
    float ss = x * x;
    #pragma unroll
    for (int off = 32; off >= 1; off >>= 1) ss += __shfl_xor(ss, off, 64);
    const float s = g[ridx] / sqrtf(ss);
    if (lane == 0) biasout[ridx] = b[ridx];
    wout[(size_t)ridx * 64 + lane] = x * s;
}

__global__ __launch_bounds__(256) void prep_kernel(PrepArgs a)
{
    const int bid = blockIdx.x, wave = threadIdx.x >> 6, lane = threadIdx.x & 63;
    if (bid < 10240)      prep_row<480, 512>(a.v0, a.g0, a.b0, a.adj, 512, 1, a.w0, a.bias0, bid * 4 + wave, lane);
    else if (bid < 15360) prep_row<512, 512>(a.v1, a.g1, a.b1, a.adj, 256, 1, a.w1, a.bias1, (bid - 10240) * 4 + wave, lane);
    else if (bid < 17920) prep_row<256, 256>(a.v2, a.g2, a.b2, a.adj, 128, 1, a.w2, a.bias2, (bid - 15360) * 4 + wave, lane);
    else if (bid < 19200) prep_row<128, 128>(a.v3, a.g3, a.b3, a.adj,  64, 0, a.w3, a.bias3, (bid - 17920) * 4 + wave, lane);
    else                  prep_w4_row(a.v4, a.g4, a.b4, a.w4, a.bias4, (bid - 19200) * 4 + wave, lane);
}

// ---------------------------------------------------------------------------
// Mega v8 = mega5 with MFMA operands swapped (W as A-operand, h as B-operand):
// reads and W layout unchanged; epilogue lane holds 4 CONSECUTIVE CHANNELS of
// one row -> aligned b64 stores (4x fewer LDS ops, ~3x less address VALU).
// h LDS byte layout identical to mega5: R0[row*C + ((o>>3 ^ row&7)<<3) + (o&7)].
// ---------------------------------------------------------------------------
struct MegaArgs {
    const float *qp, *pf, *Brff;
    const unsigned short *w0, *w1, *w2, *w3;
    const float *w4, *bias0, *bias1, *bias2, *bias3, *bias4;
    float* out;
};

__global__ __launch_bounds__(512, 4) void mega8_kernel(MegaArgs a)
{
    extern __shared__ __align__(16) unsigned short R0[];   // 32768 shorts = 64 KB
    const int tid = threadIdx.x, wid = tid >> 6, lane = tid & 63;
    const int l15 = lane & 15, l4 = lane >> 4;
    const int bid = blockIdx.x;
    const int swz = (bid & 7) * 320 + (bid >> 3);   // XCD-chunked, bijective (2560%8==0)
    const int kj = swz >> 5;
    const int m0 = (swz & 31) * 64;

    // ---- prologue: h0 = pf + RFF(qp)  -> R0 as [64][512] (480 real + 32 zero-pad)
    {
        const int row = tid >> 3;                 // 0..63
        const int tq  = tid & 7;
        const int gr  = (m0 + row) * 80 + kj;     // batch-major global row
        const float q0 = a.qp[gr * 3 + 0], q1 = a.qp[gr * 3 + 1], q2 = a.qp[gr * 3 + 2];
        #pragma unroll
        for (int i = 0; i < 8; i++) {
            const int c0 = tq * 8 + i * 64;       // multiples of 8, 0..504
            unsigned short o[8];
            if (c0 < 480) {
                const bool issin = (c0 >= 240);
                const int j0 = issin ? (c0 - 240) : c0;
                const f32x4 b0a = *reinterpret_cast<const f32x4*>(&a.Brff[j0]);
                const f32x4 b0b = *reinterpret_cast<const f32x4*>(&a.Brff[j0 + 4]);
                const f32x4 b1a = *reinterpret_cast<const f32x4*>(&a.Brff[240 + j0]);
                const f32x4 b1b = *reinterpret_cast<const f32x4*>(&a.Brff[240 + j0 + 4]);
                const f32x4 b2a = *reinterpret_cast<const f32x4*>(&a.Brff[480 + j0]);
                const f32x4 b2b = *reinterpret_cast<const f32x4*>(&a.Brff[480 + j0 + 4]);
                const f32x4 p0 = __builtin_nontemporal_load(
                    reinterpret_cast<const f32x4*>(&a.pf[(size_t)gr * 480 + c0]));
                const f32x4 p1 = __builtin_nontemporal_load(
                    reinterpret_cast<const f32x4*>(&a.pf[(size_t)gr * 480 + c0 + 4]));
                #pragma unroll
                for (int e = 0; e < 4; e++) {
                    float rev = q0 * b0a[e] + q1 * b1a[e] + q2 * b2a[e];
                    rev -= floorf(rev);           // v_sin/v_cos take revolutions
                    float t = issin ? __builtin_amdgcn_sinf(rev) : __builtin_amdgcn_cosf(rev);
                    o[e] = f2h(p0[e] + t);
                }
                #pragma unroll
                for (int e = 0; e < 4; e++) {
                    float rev = q0 * b0b[e] + q1 * b1b[e] + q2 * b2b[e];
                    rev -= floorf(rev);
                    float t = issin ? __builtin_amdgcn_sinf(rev) : __builtin_amdgcn_cosf(rev);
                    o[4 + e] = f2h(p1[e] + t);
                }
            } else {
                #pragma unroll
                for (int e = 0; e < 8; e++) o[e] = 0;
            }
            const int ck = c0 >> 3;
            *reinterpret_cast<s16x8*>(&R0[row * 512 + ((ck ^ (row & 7)) << 3)]) =
                *reinterpret_cast<const s16x8*>(o);
        }
    }
    __syncthreads();

    // ---- stage 0: h1 = leaky(h0 @ w0^T + b0).  N=512 (wave owns 64 cols), K=512.
    {
        const unsigned short* Wb = a.w0 + (size_t)kj * 262144 + (size_t)(wid * 4) * 512 + lane * 8;
        f32x4 acc[4][4] = {};
        f16x8 bfA[4], bfB[4];
        #pragma unroll
        for (int g = 0; g < 4; g++) bfA[g] = *reinterpret_cast<const f16x8*>(Wb + g * 512);
        #pragma unroll
        for (int ss = 0; ss < 8; ss++) {
            const int s0 = ss * 2, s1 = ss * 2 + 1;
            f16x8 af0[4];
            #pragma unroll
            for (int f = 0; f < 4; f++) {
                const int r = f * 16 + l15;
                af0[f] = *reinterpret_cast<const f16x8*>(&R0[r * 512 + (((s0 * 4 + l4) ^ (r & 7)) << 3)]);
            }
            #pragma unroll
            for (int g = 0; g < 4; g++)
                bfB[g] = *reinterpret_cast<const f16x8*>(Wb + (size_t)s1 * 16384 + g * 512);
            #pragma unroll
            for (int f = 0; f < 4; f++)
                #pragma unroll
                for (int g = 0; g < 4; g++)
                    MFMA16(bfA[g], af0[f], acc[f][g]);
            f16x8 af1[4];
            #pragma unroll
            for (int f = 0; f < 4; f++) {
                const int r = f * 16 + l15;
                af1[f] = *reinterpret_cast<const f16x8*>(&R0[r * 512 + (((s1 * 4 + l4) ^ (r & 7)) << 3)]);
            }
            if (ss < 7) {
                #pragma unroll
                for (int g = 0; g < 4; g++)
                    bfA[g] = *reinterpret_cast<const f16x8*>(Wb + (size_t)(s0 + 2) * 16384 + g * 512);
            }
            #pragma unroll
            for (int f = 0; f < 4; f++)
                #pragma unroll
                for (int g = 0; g < 4; g++)
                    MFMA16(bfB[g], af1[f], acc[f][g]);
        }
        __syncthreads();                          // all h0 reads done
        #pragma unroll
        for (int g = 0; g < 4; g++) {
            const f32x4 bv = *reinterpret_cast<const f32x4*>(
                &a.bias0[kj * 512 + wid * 64 + g * 16 + l4 * 4]);
            const int o = wid * 64 + g * 16 + l4 * 4;
            #pragma unroll
            for (int f = 0; f < 4; f++) {
                unsigned short o4[4];
                #pragma unroll
                for (int r = 0; r < 4; r++) {
                    float z = acc[f][g][r] + bv[r];
                    z = z >= 0.f ? z : 0.01f * z;
                    o4[r] = f2h(z);
                }
                const int row = f * 16 + l15;
                *reinterpret_cast<s16x4*>(
                    &R0[row * 512 + (((o >> 3) ^ (row & 7)) << 3) + (o & 7)]) =
                    *reinterpret_cast<const s16x4*>(o4);
            }
        }
    }
    __syncthreads();

    // ---- stage 1: h2 = leaky(h1 @ w1^T + b1).  N=256 (wave owns 32), K=512.
    {
        const unsigned short* Wb = a.w1 + (size_t)kj * 131072 + (size_t)(wid * 2) * 512 + lane * 8;
        f32x4 acc[4][2] = {};
        f16x8 bfA[2], bfB[2];
        #pragma unroll
        for (int g = 0; g < 2; g++) bfA[g] = *reinterpret_cast<const f16x8*>(Wb + g * 512);
        #pragma unroll
        for (int ss = 0; ss < 8; ss++) {
            const int s0 = ss * 2, s1 = ss * 2 + 1;
            f16x8 af0[4];
            #pragma unroll
            for (int f = 0; f < 4; f++) {
                const int r = f * 16 + l15;
                af0[f] = *reinterpret_cast<const f16x8*>(&R0[r * 512 + (((s0 * 4 + l4) ^ (r & 7)) << 3)]);
            }
            #pragma unroll
            for (int g = 0; g < 2; g++)
                bfB[g] = *reinterpret_cast<const f16x8*>(Wb + (size_t)s1 * 8192 + g * 512);
            #pragma unroll
            for (int f = 0; f < 4; f++)
                #pragma unroll
                for (int g = 0; g < 2; g++)
                    MFMA16(bfA[g], af0[f], acc[f][g]);
            f16x8 af1[4];
            #pragma unroll
            for (int f = 0; f < 4; f++) {
                const int r = f * 16 + l15;
                af1[f] = *reinterpret_cast<const f16x8*>(&R0[r * 512 + (((s1 * 4 + l4) ^ (r & 7)) << 3)]);
            }
            if (ss < 7) {
                #pragma unroll
                for (int g = 0; g < 2; g++)
                    bfA[g] = *reinterpret_cast<const f16x8*>(Wb + (size_t)(s0 + 2) * 8192 + g * 512);
            }
            #pragma unroll
            for (int f = 0; f < 4; f++)
                #pragma unroll
                for (int g = 0; g < 2; g++)
                    MFMA16(bfB[g], af1[f], acc[f][g]);
        }
        __syncthreads();
        #pragma unroll
        for (int g = 0; g < 2; g++) {
            const f32x4 bv = *reinterpret_cast<const f32x4*>(
                &a.bias1[kj * 256 + wid * 32 + g * 16 + l4 * 4]);
            const int o = wid * 32 + g * 16 + l4 * 4;
            #pragma unroll
            for (int f = 0; f < 4; f++) {
                unsigned short o4[4];
                #pragma unroll
                for (int r = 0; r < 4; r++) {
                    float z = acc[f][g][r] + bv[r];
                    z = z >= 0.f ? z : 0.01f * z;
                    o4[r] = f2h(z);
                }
                const int row = f * 16 + l15;
                *reinterpret_cast<s16x4*>(
                    &R0[row * 256 + (((o >> 3) ^ (row & 7)) << 3) + (o & 7)]) =
                    *reinterpret_cast<const s16x4*>(o4);
            }
        }
    }
    __syncthreads();

    // ---- stage 2: h3 = leaky(h2 @ w2^T + b2).  N=128 (wave owns 16), K=256.
    {
        const unsigned short* Wb = a.w2 + (size_t)kj * 32768 + (size_t)wid * 512 + lane * 8;
        f32x4 acc[4] = {};
        f16x8 bfA, bfB;
        bfA = *reinterpret_cast<const f16x8*>(Wb);
        #pragma unroll
        for (int ss = 0; ss < 4; ss++) {
            const int s0 = ss * 2, s1 = ss * 2 + 1;
            f16x8 af0[4];
            #pragma unroll
            for (int f = 0; f < 4; f++) {
                const int r = f * 16 + l15;
                af0[f] = *reinterpret_cast<const f16x8*>(&R0[r * 256 + (((s0 * 4 + l4) ^ (r & 7)) << 3)]);
            }
            bfB = *reinterpret_cast<const f16x8*>(Wb + (size_t)s1 * 4096);
            #pragma unroll
            for (int f = 0; f < 4; f++)
                MFMA16(bfA, af0[f], acc[f]);
            f16x8 af1[4];
            #pragma unroll
            for (int f = 0; f < 4; f++) {
                const int r = f * 16 + l15;
                af1[f] = *reinterpret_cast<const f16x8*>(&R0[r * 256 + (((s1 * 4 + l4) ^ (r & 7)) << 3)]);
            }
            if (ss < 3) bfA = *reinterpret_cast<const f16x8*>(Wb + (size_t)(s0 + 2) * 4096);
            #pragma unroll
            for (int f = 0; f < 4; f++)
                MFMA16(bfB, af1[f], acc[f]);
        }
        __syncthreads();
        {
            const f32x4 bv = *reinterpret_cast<const f32x4*>(
                &a.bias2[kj * 128 + wid * 16 + l4 * 4]);
            const int o = wid * 16 + l4 * 4;
            #pragma unroll
            for (int f = 0; f < 4; f++) {
                unsigned short o4[4];
                #pragma unroll
                for (int r = 0; r < 4; r++) {
                    float z = acc[f][r] + bv[r];
                    z = z >= 0.f ? z : 0.01f * z;
                    o4[r] = f2h(z);
                }
                const int row = f * 16 + l15;
                *reinterpret_cast<s16x4*>(
                    &R0[row * 128 + (((o >> 3) ^ (row & 7)) << 3) + (o & 7)]) =
                    *reinterpret_cast<const s16x4*>(o4);
            }
        }
    }
    __syncthreads();

    // ---- stage 3: h4 = leaky(h3 @ w3^T + b3).  N=64, K=128. Waves 2M x 4N.
    {
        const int wm = wid >> 2, wn4 = wid & 3;
        const unsigned short* Wb = a.w3 + (size_t)kj * 8192 + (size_t)wn4 * 512 + lane * 8;
        f32x4 acc[2] = {};
        #pragma unroll
        for (int s = 0; s < 4; s++) {
            f16x8 af[2], bf;
            #pragma unroll
            for (int f = 0; f < 2; f++) {
                const int r = wm * 32 + f * 16 + l15;
                af[f] = *reinterpret_cast<const f16x8*>(&R0[r * 128 + (((s * 4 + l4) ^ (r & 7)) << 3)]);
            }
            bf = *reinterpret_cast<const f16x8*>(Wb + (size_t)s * 2048);
            #pragma unroll
            for (int f = 0; f < 2; f++)
                MFMA16(bf, af[f], acc[f]);
        }
        __syncthreads();
        {
            const f32x4 bv = *reinterpret_cast<const f32x4*>(
                &a.bias3[kj * 64 + wn4 * 16 + l4 * 4]);
            const int o = wn4 * 16 + l4 * 4;
            #pragma unroll
            for (int f = 0; f < 2; f++) {
                unsigned short o4[4];
                #pragma unroll
                for (int r = 0; r < 4; r++) {
                    float z = acc[f][r] + bv[r];
                    z = z >= 0.f ? z : 0.01f * z;
                    o4[r] = f2h(z);
                }
                const int row = wm * 32 + f * 16 + l15;
                *reinterpret_cast<s16x4*>(
                    &R0[row * 64 + (((o >> 3) ^ (row & 7)) << 3) + (o & 7)]) =
                    *reinterpret_cast<const s16x4*>(o4);
            }
        }
    }
    __syncthreads();

    // ---- stage 4: out = h4 @ w4^T + b4 (f32, 6 outputs per row, NT stores).
    if (tid < 64) {
        const int row = tid;
        float xv[64];
        #pragma unroll
        for (int ch = 0; ch < 8; ch++) {
            s16x8 v = *reinterpret_cast<const s16x8*>(&R0[row * 64 + ((ch ^ (row & 7)) << 3)]);
            #pragma unroll
            for (int e = 0; e < 8; e++) xv[ch * 8 + e] = h2f((unsigned short)v[e]);
        }
        const float* w4b = a.w4 + kj * 384;
        float* op = a.out + ((size_t)(m0 + row) * 80 + kj) * 6;
        #pragma unroll
        for (int o = 0; o < 6; o++) {
            float sum = a.bias4[kj * 6 + o];
            #pragma unroll
            for (int i = 0; i < 64; i++) sum = fmaf(xv[i], w4b[o * 64 + i], sum);
            __builtin_nontemporal_store(sum, &op[o]);
        }
    }
}

// ---------------------------------------------------------------------------
extern "C" void kernel_launch(void* const* d_in, const int* in_sizes, int n_in,
                              void* d_out, int out_size, void* d_ws, size_t ws_size,
                              hipStream_t stream)
{
    (void)in_sizes; (void)n_in; (void)out_size; (void)ws_size;
    PrepArgs a;
    a.adj  = (const float*)d_in[2];
    a.v0 = (const float*)d_in[4];  a.g0 = (const float*)d_in[5];  a.b0 = (const float*)d_in[6];
    a.v1 = (const float*)d_in[7];  a.g1 = (const float*)d_in[8];  a.b1 = (const float*)d_in[9];
    a.v2 = (const float*)d_in[10]; a.g2 = (const float*)d_in[11]; a.b2 = (const float*)d_in[12];
    a.v3 = (const float*)d_in[13]; a.g3 = (const float*)d_in[14]; a.b3 = (const float*)d_in[15];
    a.v4 = (const float*)d_in[16]; a.g4 = (const float*)d_in[17]; a.b4 = (const float*)d_in[18];

    char* ws = (char*)d_ws;
    size_t off = 0;
    auto alloc = [&](size_t n) -> void* {
        off = (off + 255) & ~(size_t)255;
        void* p = ws + off;
        off += n;
        return p;
    };
    a.w0 = (unsigned short*)alloc(80ull * 512 * 512 * 2);
    a.w1 = (unsigned short*)alloc(80ull * 256 * 512 * 2);
    a.w2 = (unsigned short*)alloc(80ull * 128 * 256 * 2);
    a.w3 = (unsigned short*)alloc(80ull * 64 * 128 * 2);
    a.w4 = (float*)alloc(80ull * 6 * 64 * 4);
    a.bias0 = (float*)alloc(80ull * 512 * 4);
    a.bias1 = (float*)alloc(80ull * 256 * 4);
    a.bias2 = (float*)alloc(80ull * 128 * 4);
    a.bias3 = (float*)alloc(80ull * 64 * 4);
    a.bias4 = (float*)alloc(80ull * 6 * 4);

    MegaArgs m;
    m.qp   = (const float*)d_in[0];
    m.pf   = (const float*)d_in[1];
    m.Brff = (const float*)d_in[3];
    m.w0 = a.w0; m.w1 = a.w1; m.w2 = a.w2; m.w3 = a.w3; m.w4 = a.w4;
    m.bias0 = a.bias0; m.bias1 = a.bias1; m.bias2 = a.bias2;
    m.bias3 = a.bias3; m.bias4 = a.bias4;
    m.out = (float*)d_out;

    (void)hipFuncSetAttribute((const void*)mega8_kernel,
                              hipFuncAttributeMaxDynamicSharedMemorySize, 65536);

    prep_kernel<<<19320, 256, 0, stream>>>(a);
    mega8_kernel<<<2560, 512, 65536, stream>>>(m);
}